// Round 3
// baseline (1131.216 us; speedup 1.0000x reference)
//
#include <hip/hip_runtime.h>
#include <stdint.h>
#include <math.h>

typedef float f4 __attribute__((ext_vector_type(4)));

// ---------------- Threefry-2x32 (exact JAX replication) ----------------
static __device__ __forceinline__ uint32_t rotl32(uint32_t x, int r) {
    return (x << r) | (x >> (32 - r));
}

static __device__ __forceinline__ void tf2x32(uint32_t k0, uint32_t k1,
                                              uint32_t& x0, uint32_t& x1) {
    uint32_t ks2 = k0 ^ k1 ^ 0x1BD11BDAu;
    x0 += k0; x1 += k1;
#define TFR(r) { x0 += x1; x1 = rotl32(x1, r); x1 ^= x0; }
    TFR(13) TFR(15) TFR(26) TFR(6)
    x0 += k1;  x1 += ks2 + 1u;
    TFR(17) TFR(29) TFR(16) TFR(24)
    x0 += ks2; x1 += k0 + 2u;
    TFR(13) TFR(15) TFR(26) TFR(6)
    x0 += k0;  x1 += k1 + 3u;
    TFR(17) TFR(29) TFR(16) TFR(24)
    x0 += k1;  x1 += ks2 + 4u;
    TFR(13) TFR(15) TFR(26) TFR(6)
    x0 += ks2; x1 += k0 + 5u;
#undef TFR
}

// jax.random.split(key(42), 3): threefry_2x32((0,42), iota(6)) reshaped (3,2).
// out = [a0,a1,a2,b0,b1,b2] where (a_i,b_i) = cipher(i, i+3)
// k1=(a0,a1)  k2=(a2,b0)  k3=(b1,b2)
struct SubKeys { uint32_t k1a, k1b, k2a, k2b, k3a, k3b; };

static __device__ __forceinline__ SubKeys derive_keys() {
    uint32_t a0 = 0, b0 = 3; tf2x32(0u, 42u, a0, b0);
    uint32_t a1 = 1, b1 = 4; tf2x32(0u, 42u, a1, b1);
    uint32_t a2 = 2, b2 = 5; tf2x32(0u, 42u, a2, b2);
    SubKeys s; s.k1a = a0; s.k1b = a1; s.k2a = a2; s.k2b = b0; s.k3a = b1; s.k3b = b2;
    return s;
}

static __device__ __forceinline__ float bits_to_unit_float(uint32_t b) {
    return __uint_as_float((b >> 9) | 0x3f800000u) - 1.0f;
}

// ---------------- shared pipeline kernels (verified) ----------------
__global__ void k_seed(const int* __restrict__ seeds, int n_seeds,
                       unsigned char* __restrict__ seedm) {
    int i = blockIdx.x * blockDim.x + threadIdx.x;
    if (i < n_seeds) seedm[seeds[i]] = 1;
}

__global__ void k_edge1(const int* __restrict__ rows, const int* __restrict__ cols, int nnz,
                        const unsigned char* __restrict__ seedm,
                        unsigned char* __restrict__ keep, unsigned char* __restrict__ nxt) {
    int e = blockIdx.x * blockDim.x + threadIdx.x;
    if (e >= nnz) return;
    int r = rows[e], c = cols[e];
    bool inc = (seedm[r] | seedm[c]) != 0;
    keep[e] = inc ? 0 : 1;
    if (inc) { nxt[r] = 1; nxt[c] = 1; }   // same-value byte stores, race-safe
}

__global__ void k_edge2(const int* __restrict__ rows, const int* __restrict__ cols, int nnz,
                        const unsigned char* __restrict__ nxt,
                        unsigned char* __restrict__ keep) {
    int e = blockIdx.x * blockDim.x + threadIdx.x;
    if (e >= nnz) return;
    if (keep[e] && ((nxt[rows[e]] | nxt[cols[e]]) != 0)) keep[e] = 0;
}

__global__ void k_union(int n, const unsigned char* __restrict__ seedm,
                        const unsigned char* __restrict__ nxt,
                        unsigned char* __restrict__ mask) {
    int i = blockIdx.x * blockDim.x + threadIdx.x;
    if (i < n) mask[i] = (unsigned char)(seedm[i] | nxt[i]);
}

// samped = randint(k1,(samp_num,),0,N) with N=2^13 -> bits & (N-1).
__global__ void k_samp(int half, int modmask, unsigned char* __restrict__ mask) {
    int t = blockIdx.x * blockDim.x + threadIdx.x;
    if (t >= half) return;
    SubKeys sk = derive_keys();
    uint32_t x0 = (uint32_t)t, x1 = (uint32_t)(t + half);
    tf2x32(sk.k1a, sk.k1b, x0, x1);
    mask[x0 & (uint32_t)modmask] = 1;
    mask[x1 & (uint32_t)modmask] = 1;
}

// single-block scan: mask (n bytes, n<=8192) -> ascending mask_idx + tem_num
__global__ void __launch_bounds__(1024)
k_scan(int n, const unsigned char* __restrict__ mask,
       int* __restrict__ mask_idx, int* __restrict__ tem_num) {
    __shared__ int ssum[1024];
    int t = threadIdx.x;
    int per = n / 1024;           // 8 for n=8192
    int base = t * per;
    int loc[8];
    int s = 0;
    for (int j = 0; j < per; ++j) { loc[j] = mask[base + j]; s += loc[j]; }
    ssum[t] = s;
    __syncthreads();
    for (int off = 1; off < 1024; off <<= 1) {
        int v = (t >= off) ? ssum[t - off] : 0;
        __syncthreads();
        ssum[t] += v;
        __syncthreads();
    }
    int excl = ssum[t] - s;
    for (int j = 0; j < per; ++j)
        if (loc[j]) mask_idx[excl++] = base + j;
    if (t == 1023) *tem_num = ssum[1023];
}

__global__ void k_deg(const int* __restrict__ rows, const int* __restrict__ cols, int nnz,
                      const unsigned char* __restrict__ keep,
                      const float* __restrict__ comp, float* __restrict__ deg, int n) {
    int e = blockIdx.x * blockDim.x + threadIdx.x;
    if (e >= nnz) return;
    if (keep[e]) {
        int r = rows[e], c = cols[e];
        atomicAdd(&deg[r], comp[(size_t)r * n + c]);
    }
}

__global__ void k_norm(int n, const float* __restrict__ deg, float* __restrict__ nrm) {
    int i = blockIdx.x * blockDim.x + threadIdx.x;
    if (i < n) nrm[i] = 1.0f / sqrtf(deg[i] + 1e-12f);
}

// ---------------- fast path: per-block LDS bitmaps, dense fused write ----------------
// 256 blocks x 512 threads; block b owns rows [32b, 32b+32).
// LDS: enc bitmap 32KB + dec bitmap 32KB + mask_idx(u16) 16KB = 80KB.
// Phase order: raster keep+diag -> write enc rows (stores drain in background)
// -> redundant tem RNG (filter to window) -> write dec rows.
#define DG 32

__global__ void __launch_bounds__(512)
k_dense_win(const int* __restrict__ rows, const int* __restrict__ cols,
            int nnz, int ehalf, int n,
            const unsigned char* __restrict__ keep,
            const int* __restrict__ mask_idx, const int* __restrict__ tem_num,
            const float* __restrict__ comp, const float* __restrict__ nrm,
            float* __restrict__ enc, float* __restrict__ dec) {
    __shared__ unsigned int sbm[16384];        // [0,8192)=enc bits, [8192,16384)=dec bits
    __shared__ unsigned short smi[8192];
    const int t = threadIdx.x;
    const int base = blockIdx.x * DG;
    const int wpr = n >> 5;                    // 256 words per row

    for (int i = t; i < 16384; i += 512) sbm[i] = 0;
    for (int i = t; i < n; i += 512) smi[i] = (unsigned short)mask_idx[i];
    __syncthreads();

    // kept edges (directed r->c): enc + dec coverage. keep is ~1-2% dense.
    for (int e = t; e < nnz; e += 512) {
        if (!keep[e]) continue;
        int r = rows[e];
        unsigned int rr = (unsigned int)(r - base);
        if (rr < DG) {
            int c = cols[e];
            unsigned int b = 1u << (c & 31);
            atomicOr(&sbm[rr * wpr + (c >> 5)], b);
            atomicOr(&sbm[8192 + rr * wpr + (c >> 5)], b);
        }
    }
    // self loops (dec only)
    if (t < DG) {
        int c = base + t;
        atomicOr(&sbm[8192 + t * wpr + (c >> 5)], 1u << (c & 31));
    }
    __syncthreads();                           // enc bitmap final; dec gets more bits below

    // ---- write enc rows now; nontemporal stores drain under the RNG phase ----
    for (int i = 0; i < DG; ++i) {
        int r = base + i;
        float nr = nrm[r];
        size_t rowo = (size_t)r * n;
        const f4* compv = (const f4*)(comp + rowo);
        const f4* nrmv  = (const f4*)nrm;
        f4* encv = (f4*)(enc + rowo);
#pragma unroll 4
        for (int f = t; f < (n >> 2); f += 512) {
            unsigned int ew = (sbm[i * wpr + (f >> 3)] >> ((f & 7) * 4)) & 0xFu;
            f4 ev = {0.f, 0.f, 0.f, 0.f};
            if (ew) {
                f4 cv = compv[f];
                f4 nv = nrmv[f];
                if (ew & 1u) ev.x = cv.x * nr * nv.x;
                if (ew & 2u) ev.y = cv.y * nr * nv.y;
                if (ew & 4u) ev.z = cv.z * nr * nv.z;
                if (ew & 8u) ev.w = cv.w * nr * nv.w;
            }
            __builtin_nontemporal_store(ev, &encv[f]);
        }
    }

    // ---- tem pairs: every block regenerates all, keeps those in its window ----
    {
        SubKeys sk = derive_keys();
        float tf = (float)(*tem_num);
        for (int e = t; e < ehalf; e += 512) {
            uint32_t u1a = (uint32_t)e, u1b = (uint32_t)(e + ehalf);
            tf2x32(sk.k2a, sk.k2b, u1a, u1b);
            uint32_t u2a = (uint32_t)e, u2b = (uint32_t)(e + ehalf);
            tf2x32(sk.k3a, sk.k3b, u2a, u2b);
#pragma unroll
            for (int j = 0; j < 2; ++j) {
                uint32_t b1 = j ? u1b : u1a;
                uint32_t b2 = j ? u2b : u2a;
                int i1 = (int)(bits_to_unit_float(b1) * tf);   // floor==trunc, f32 RN == jnp
                int i2 = (int)(bits_to_unit_float(b2) * tf);
                int r = smi[i1];
                int c = smi[i2];
                unsigned int rr = (unsigned int)(r - base);
                unsigned int cc = (unsigned int)(c - base);
                if (rr < DG) atomicOr(&sbm[8192 + rr * wpr + (c >> 5)], 1u << (c & 31));
                if (cc < DG) atomicOr(&sbm[8192 + cc * wpr + (r >> 5)], 1u << (r & 31));
            }
        }
    }
    __syncthreads();                           // dec bitmap final

    // ---- write dec rows ----
    for (int i = 0; i < DG; ++i) {
        int r = base + i;
        size_t rowo = (size_t)r * n;
        const f4* compv = (const f4*)(comp + rowo);
        f4* decv = (f4*)(dec + rowo);
#pragma unroll 4
        for (int f = t; f < (n >> 2); f += 512) {
            unsigned int dw = (sbm[8192 + i * wpr + (f >> 3)] >> ((f & 7) * 4)) & 0xFu;
            f4 dv = {0.f, 0.f, 0.f, 0.f};
            if (dw) {
                f4 cv = compv[f];
                if (dw & 1u) dv.x = cv.x;
                if (dw & 2u) dv.y = cv.y;
                if (dw & 4u) dv.z = cv.z;
                if (dw & 8u) dv.w = cv.w;
            }
            __builtin_nontemporal_store(dv, &decv[f]);
        }
    }
}

// ---------------- fallback path (previous verified kernels) ----------------
__global__ void k_enc(const int* __restrict__ rows, const int* __restrict__ cols, int nnz,
                      const unsigned char* __restrict__ keep,
                      const float* __restrict__ comp, const float* __restrict__ nrm,
                      float* __restrict__ enc, int n) {
    int e = blockIdx.x * blockDim.x + threadIdx.x;
    if (e >= nnz) return;
    if (keep[e]) {
        int r = rows[e], c = cols[e];
        size_t o = (size_t)r * n + c;
        enc[o] = comp[o] * nrm[r] * nrm[c];
    }
}

__global__ void k_dec_base(const int* __restrict__ rows, const int* __restrict__ cols,
                           int nnz, int n, const unsigned char* __restrict__ keep,
                           const float* __restrict__ comp, float* __restrict__ dec) {
    int e = blockIdx.x * blockDim.x + threadIdx.x;
    if (e < nnz) {
        if (keep[e]) {
            size_t o = (size_t)rows[e] * n + cols[e];
            dec[o] = comp[o];
        }
    } else if (e < nnz + n) {
        int i = e - nnz;
        size_t o = (size_t)i * n + i;
        dec[o] = comp[o];
    }
}

__global__ void k_dec_tem(int half, int n, const int* __restrict__ mask_idx,
                          const int* __restrict__ tem_num,
                          const float* __restrict__ comp, float* __restrict__ dec) {
    int e = blockIdx.x * blockDim.x + threadIdx.x;
    if (e >= half) return;
    SubKeys sk = derive_keys();
    float tf = (float)(*tem_num);
    uint32_t u1a = (uint32_t)e, u1b = (uint32_t)(e + half);
    tf2x32(sk.k2a, sk.k2b, u1a, u1b);
    uint32_t u2a = (uint32_t)e, u2b = (uint32_t)(e + half);
    tf2x32(sk.k3a, sk.k3b, u2a, u2b);
#pragma unroll
    for (int j = 0; j < 2; ++j) {
        uint32_t b1 = j ? u1b : u1a;
        uint32_t b2 = j ? u2b : u2a;
        int i1 = (int)(bits_to_unit_float(b1) * tf);
        int i2 = (int)(bits_to_unit_float(b2) * tf);
        int r = mask_idx[i1];
        int c = mask_idx[i2];
        size_t o1 = (size_t)r * n + c;
        size_t o2 = (size_t)c * n + r;
        dec[o1] = comp[o1];
        dec[o2] = comp[o2];
    }
}

// ---------------- launch ----------------
extern "C" void kernel_launch(void* const* d_in, const int* in_sizes, int n_in,
                              void* d_out, int out_size, void* d_ws, size_t ws_size,
                              hipStream_t stream) {
    const int*   rows  = (const int*)d_in[0];
    const int*   cols  = (const int*)d_in[1];
    // d_in[2] = adj_values — unused by the forward
    const int*   seeds = (const int*)d_in[3];
    const float* comp  = (const float*)d_in[4];

    const int nnz     = in_sizes[0];
    const int n_seeds = in_sizes[3];
    const int n       = (int)(sqrt((double)in_sizes[4]) + 0.5);   // 8192

    float* enc = (float*)d_out;
    float* dec = enc + (size_t)n * n;

    // ---- small workspace region (identical to the originally verified layout,
    //      ~385 KB — the ONLY workspace this kernel requires) ----
    char* ws = (char*)d_ws;
    float* deg            = (float*)(ws);
    float* nrm            = (float*)(ws + 4 * (size_t)n);
    int*   mask_idx       = (int*)  (ws + 8 * (size_t)n);
    int*   tem_num        = (int*)  (ws + 12 * (size_t)n);
    unsigned char* seedm  = (unsigned char*)(ws + 12 * (size_t)n + 256);
    unsigned char* nxt    = seedm + n;
    unsigned char* mask   = nxt + n;
    unsigned char* keep   = mask + n;   // nnz bytes, fully written each call

    const int B = 256;
    int samp_num = (int)((double)n * 0.9);   // int(N*0.9) = 7372 (even)
    int shalf = samp_num / 2;
    int ehalf = nnz / 2;

    // zero: deg..tem_num + seedm/nxt/mask (NOT keep — fully written by k_edge1)
    size_t zbytes = 12 * (size_t)n + 256 + 3 * (size_t)n;
    hipMemsetAsync(d_ws, 0, zbytes, stream);

    k_seed <<<(n_seeds + B - 1) / B, B, 0, stream>>>(seeds, n_seeds, seedm);
    k_edge1<<<(nnz + B - 1) / B, B, 0, stream>>>(rows, cols, nnz, seedm, keep, nxt);
    k_edge2<<<(nnz + B - 1) / B, B, 0, stream>>>(rows, cols, nnz, nxt, keep);
    k_union<<<(n + B - 1) / B, B, 0, stream>>>(n, seedm, nxt, mask);
    k_samp <<<(shalf + B - 1) / B, B, 0, stream>>>(shalf, n - 1, mask);
    k_scan <<<1, 1024, 0, stream>>>(n, mask, mask_idx, tem_num);
    k_deg  <<<(nnz + B - 1) / B, B, 0, stream>>>(rows, cols, nnz, keep, comp, deg, n);
    k_norm <<<(n + B - 1) / B, B, 0, stream>>>(n, deg, nrm);

    if (n == 8192) {
        // dense fused writer: no d_out memset, every output byte written once.
        k_dense_win<<<n / DG, 512, 0, stream>>>(rows, cols, nnz, ehalf, n,
                                                keep, mask_idx, tem_num,
                                                comp, nrm, enc, dec);
    } else {
        // legacy scattered path for unexpected shapes
        hipMemsetAsync(d_out, 0, 2 * (size_t)n * (size_t)n * sizeof(float), stream);
        k_enc  <<<(nnz + B - 1) / B, B, 0, stream>>>(rows, cols, nnz, keep, comp, nrm, enc, n);
        k_dec_base<<<(nnz + n + B - 1) / B, B, 0, stream>>>(rows, cols, nnz, n, keep, comp, dec);
        k_dec_tem<<<(ehalf + B - 1) / B, B, 0, stream>>>(ehalf, n, mask_idx, tem_num, comp, dec);
    }
}

// Round 4
// 751.637 us; speedup vs baseline: 1.5050x; 1.5050x over previous
//
#include <hip/hip_runtime.h>
#include <stdint.h>
#include <math.h>

typedef float f4 __attribute__((ext_vector_type(4)));
typedef unsigned int u32;
typedef uint4 u32x4;

// ---------------- Threefry-2x32 (exact JAX replication) ----------------
static __device__ __forceinline__ uint32_t rotl32(uint32_t x, int r) {
    return (x << r) | (x >> (32 - r));
}

static __device__ __forceinline__ void tf2x32(uint32_t k0, uint32_t k1,
                                              uint32_t& x0, uint32_t& x1) {
    uint32_t ks2 = k0 ^ k1 ^ 0x1BD11BDAu;
    x0 += k0; x1 += k1;
#define TFR(r) { x0 += x1; x1 = rotl32(x1, r); x1 ^= x0; }
    TFR(13) TFR(15) TFR(26) TFR(6)
    x0 += k1;  x1 += ks2 + 1u;
    TFR(17) TFR(29) TFR(16) TFR(24)
    x0 += ks2; x1 += k0 + 2u;
    TFR(13) TFR(15) TFR(26) TFR(6)
    x0 += k0;  x1 += k1 + 3u;
    TFR(17) TFR(29) TFR(16) TFR(24)
    x0 += k1;  x1 += ks2 + 4u;
    TFR(13) TFR(15) TFR(26) TFR(6)
    x0 += ks2; x1 += k0 + 5u;
#undef TFR
}

// jax.random.split(key(42), 3): threefry_2x32((0,42), iota(6)) reshaped (3,2).
// k1=(a0,a1)  k2=(a2,b0)  k3=(b1,b2)
struct SubKeys { uint32_t k1a, k1b, k2a, k2b, k3a, k3b; };

static __device__ __forceinline__ SubKeys derive_keys() {
    uint32_t a0 = 0, b0 = 3; tf2x32(0u, 42u, a0, b0);
    uint32_t a1 = 1, b1 = 4; tf2x32(0u, 42u, a1, b1);
    uint32_t a2 = 2, b2 = 5; tf2x32(0u, 42u, a2, b2);
    SubKeys s; s.k1a = a0; s.k1b = a1; s.k2a = a2; s.k2b = b0; s.k3a = b1; s.k3b = b2;
    return s;
}

static __device__ __forceinline__ float bits_to_unit_float(uint32_t b) {
    return __uint_as_float((b >> 9) | 0x3f800000u) - 1.0f;
}

// ---------------- shared pipeline kernels (verified) ----------------
__global__ void k_seed(const int* __restrict__ seeds, int n_seeds,
                       unsigned char* __restrict__ seedm) {
    int i = blockIdx.x * blockDim.x + threadIdx.x;
    if (i < n_seeds) seedm[seeds[i]] = 1;
}

__global__ void k_edge1(const int* __restrict__ rows, const int* __restrict__ cols, int nnz,
                        const unsigned char* __restrict__ seedm,
                        unsigned char* __restrict__ keep, unsigned char* __restrict__ nxt) {
    int e = blockIdx.x * blockDim.x + threadIdx.x;
    if (e >= nnz) return;
    int r = rows[e], c = cols[e];
    bool inc = (seedm[r] | seedm[c]) != 0;
    keep[e] = inc ? 0 : 1;
    if (inc) { nxt[r] = 1; nxt[c] = 1; }   // same-value byte stores, race-safe
}

__global__ void k_edge2(const int* __restrict__ rows, const int* __restrict__ cols, int nnz,
                        const unsigned char* __restrict__ nxt,
                        unsigned char* __restrict__ keep) {
    int e = blockIdx.x * blockDim.x + threadIdx.x;
    if (e >= nnz) return;
    if (keep[e] && ((nxt[rows[e]] | nxt[cols[e]]) != 0)) keep[e] = 0;
}

__global__ void k_union(int n, const unsigned char* __restrict__ seedm,
                        const unsigned char* __restrict__ nxt,
                        unsigned char* __restrict__ mask) {
    int i = blockIdx.x * blockDim.x + threadIdx.x;
    if (i < n) mask[i] = (unsigned char)(seedm[i] | nxt[i]);
}

// samped = randint(k1,(samp_num,),0,N) with N=2^13 -> bits & (N-1).
__global__ void k_samp(int half, int modmask, unsigned char* __restrict__ mask) {
    int t = blockIdx.x * blockDim.x + threadIdx.x;
    if (t >= half) return;
    SubKeys sk = derive_keys();
    uint32_t x0 = (uint32_t)t, x1 = (uint32_t)(t + half);
    tf2x32(sk.k1a, sk.k1b, x0, x1);
    mask[x0 & (uint32_t)modmask] = 1;
    mask[x1 & (uint32_t)modmask] = 1;
}

// single-block scan: mask (n bytes, n<=8192) -> ascending mask_idx + tem_num
__global__ void __launch_bounds__(1024)
k_scan(int n, const unsigned char* __restrict__ mask,
       int* __restrict__ mask_idx, int* __restrict__ tem_num) {
    __shared__ int ssum[1024];
    int t = threadIdx.x;
    int per = n / 1024;           // 8 for n=8192
    int base = t * per;
    int loc[8];
    int s = 0;
    for (int j = 0; j < per; ++j) { loc[j] = mask[base + j]; s += loc[j]; }
    ssum[t] = s;
    __syncthreads();
    for (int off = 1; off < 1024; off <<= 1) {
        int v = (t >= off) ? ssum[t - off] : 0;
        __syncthreads();
        ssum[t] += v;
        __syncthreads();
    }
    int excl = ssum[t] - s;
    for (int j = 0; j < per; ++j)
        if (loc[j]) mask_idx[excl++] = base + j;
    if (t == 1023) *tem_num = ssum[1023];
}

__global__ void k_deg(const int* __restrict__ rows, const int* __restrict__ cols, int nnz,
                      const unsigned char* __restrict__ keep,
                      const float* __restrict__ comp, float* __restrict__ deg, int n) {
    int e = blockIdx.x * blockDim.x + threadIdx.x;
    if (e >= nnz) return;
    if (keep[e]) {
        int r = rows[e], c = cols[e];
        atomicAdd(&deg[r], comp[(size_t)r * n + c]);
    }
}

__global__ void k_norm(int n, const float* __restrict__ deg, float* __restrict__ nrm) {
    int i = blockIdx.x * blockDim.x + threadIdx.x;
    if (i < n) nrm[i] = 1.0f / sqrtf(deg[i] + 1e-12f);
}

// ---------------- fast path (n==8192): scratch-in-window coverage bitmaps ----------------
// Window b = dec rows [32b, 32b+32). Its 64KB bitmap slice (8192 u32 dec bits,
// then 8192 u32 enc bits) lives in its OWN first two rows:
//   slice(b) = (u32*)dec + b*262144    (262144 u32 = 32 rows * 8192 floats)
// No block ever reads another block's window -> no cross-block ordering needed.
#define WPR   256          // u32 words per bitmap row (8192/32)
#define WIN   262144       // u32 stride between windows (32 rows * 8192)
#define SLW   16384        // u32 words per slice (2 * 8192)

// zero all 256 slices (strided 64KB every 1MB)
__global__ void __launch_bounds__(256)
k_zslice(u32* __restrict__ decw) {
    u32x4* s4 = (u32x4*)(decw + (size_t)blockIdx.x * WIN);
    for (int i = threadIdx.x; i < SLW / 4; i += 256) {
        u32x4 z = {0u, 0u, 0u, 0u};
        s4[i] = z;
    }
}

// one pass: kept edges (enc+dec), diagonal (dec), tem RNG pairs (dec, symmetric)
__global__ void __launch_bounds__(256)
k_cov(const int* __restrict__ rows, const int* __restrict__ cols,
      int nnz, int n, int ehalf,
      const unsigned char* __restrict__ keep,
      const int* __restrict__ mask_idx, const int* __restrict__ tem_num,
      u32* __restrict__ decw) {
    int e = blockIdx.x * blockDim.x + threadIdx.x;
    if (e < nnz) {
        if (keep[e]) {
            int r = rows[e], c = cols[e];
            u32* base = decw + (size_t)(r >> 5) * WIN;
            int w = ((r & 31) << 8) + (c >> 5);
            u32 b = 1u << (c & 31);
            atomicOr(&base[w], b);            // dec bit
            atomicOr(&base[8192 + w], b);     // enc bit
        }
    } else if (e < nnz + n) {
        int i = e - nnz;
        atomicOr(&decw[(size_t)(i >> 5) * WIN + ((i & 31) << 8) + (i >> 5)],
                 1u << (i & 31));             // self loop (dec)
    } else if (e < nnz + n + ehalf) {
        int q = e - nnz - n;
        SubKeys sk = derive_keys();
        float tf = (float)(*tem_num);
        uint32_t u1a = (uint32_t)q, u1b = (uint32_t)(q + ehalf);
        tf2x32(sk.k2a, sk.k2b, u1a, u1b);
        uint32_t u2a = (uint32_t)q, u2b = (uint32_t)(q + ehalf);
        tf2x32(sk.k3a, sk.k3b, u2a, u2b);
#pragma unroll
        for (int j = 0; j < 2; ++j) {
            uint32_t b1 = j ? u1b : u1a;
            uint32_t b2 = j ? u2b : u2a;
            int i1 = (int)(bits_to_unit_float(b1) * tf);   // floor==trunc, f32 RN == jnp
            int i2 = (int)(bits_to_unit_float(b2) * tf);
            int r = mask_idx[i1];
            int c = mask_idx[i2];
            atomicOr(&decw[(size_t)(r >> 5) * WIN + ((r & 31) << 8) + (c >> 5)],
                     1u << (c & 31));
            atomicOr(&decw[(size_t)(c >> 5) * WIN + ((c & 31) << 8) + (r >> 5)],
                     1u << (r & 31));
        }
    }
}

// pure streamer: load own 64KB slice -> LDS, then write 32 enc+dec rows fused.
__global__ void __launch_bounds__(512)
k_dense2(int n, const float* __restrict__ comp, const float* __restrict__ nrm,
         float* __restrict__ enc, float* __restrict__ dec) {
    __shared__ u32 sdec[8192], senc[8192];
    const int t = threadIdx.x;
    const int b = blockIdx.x;
    // coalesced slice load (4096 uint4)
    {
        const u32x4* s4 = (const u32x4*)((const u32*)dec + (size_t)b * WIN);
        u32x4* ld = (u32x4*)sdec;
        u32x4* le = (u32x4*)senc;
        for (int i = t; i < SLW / 4; i += 512) {
            u32x4 v = s4[i];
            if (i < 2048) ld[i] = v; else le[i - 2048] = v;
        }
    }
    __syncthreads();
    const int base = b * 32;
    const f4* nrmv = (const f4*)nrm;
    for (int i = 0; i < 32; ++i) {
        int r = base + i;
        float nr = nrm[r];
        size_t rowo = (size_t)r * n;
        const f4* compv = (const f4*)(comp + rowo);
        f4* encv = (f4*)(enc + rowo);
        f4* decv = (f4*)(dec + rowo);
        int wrow = i << 8;
#pragma unroll
        for (int k = 0; k < 4; ++k) {        // 2048 f4 / 512 threads
            int f = k * 512 + t;
            int sh = (f & 7) * 4;
            u32 ew = (senc[wrow + (f >> 3)] >> sh) & 0xFu;
            u32 dw = (sdec[wrow + (f >> 3)] >> sh) & 0xFu;
            f4 ev = {0.f, 0.f, 0.f, 0.f};
            f4 dv = {0.f, 0.f, 0.f, 0.f};
            if (ew | dw) {
                f4 cv = compv[f];
                if (dw & 1u) dv.x = cv.x;
                if (dw & 2u) dv.y = cv.y;
                if (dw & 4u) dv.z = cv.z;
                if (dw & 8u) dv.w = cv.w;
                if (ew) {
                    f4 nv = nrmv[f];
                    if (ew & 1u) ev.x = cv.x * nr * nv.x;
                    if (ew & 2u) ev.y = cv.y * nr * nv.y;
                    if (ew & 4u) ev.z = cv.z * nr * nv.z;
                    if (ew & 8u) ev.w = cv.w * nr * nv.w;
                }
            }
            __builtin_nontemporal_store(ev, &encv[f]);
            __builtin_nontemporal_store(dv, &decv[f]);
        }
    }
}

// ---------------- fallback path (verified scattered kernels, n != 8192) ----------------
__global__ void k_enc(const int* __restrict__ rows, const int* __restrict__ cols, int nnz,
                      const unsigned char* __restrict__ keep,
                      const float* __restrict__ comp, const float* __restrict__ nrm,
                      float* __restrict__ enc, int n) {
    int e = blockIdx.x * blockDim.x + threadIdx.x;
    if (e >= nnz) return;
    if (keep[e]) {
        int r = rows[e], c = cols[e];
        size_t o = (size_t)r * n + c;
        enc[o] = comp[o] * nrm[r] * nrm[c];
    }
}

__global__ void k_dec_base(const int* __restrict__ rows, const int* __restrict__ cols,
                           int nnz, int n, const unsigned char* __restrict__ keep,
                           const float* __restrict__ comp, float* __restrict__ dec) {
    int e = blockIdx.x * blockDim.x + threadIdx.x;
    if (e < nnz) {
        if (keep[e]) {
            size_t o = (size_t)rows[e] * n + cols[e];
            dec[o] = comp[o];
        }
    } else if (e < nnz + n) {
        int i = e - nnz;
        size_t o = (size_t)i * n + i;
        dec[o] = comp[o];
    }
}

__global__ void k_dec_tem(int half, int n, const int* __restrict__ mask_idx,
                          const int* __restrict__ tem_num,
                          const float* __restrict__ comp, float* __restrict__ dec) {
    int e = blockIdx.x * blockDim.x + threadIdx.x;
    if (e >= half) return;
    SubKeys sk = derive_keys();
    float tf = (float)(*tem_num);
    uint32_t u1a = (uint32_t)e, u1b = (uint32_t)(e + half);
    tf2x32(sk.k2a, sk.k2b, u1a, u1b);
    uint32_t u2a = (uint32_t)e, u2b = (uint32_t)(e + half);
    tf2x32(sk.k3a, sk.k3b, u2a, u2b);
#pragma unroll
    for (int j = 0; j < 2; ++j) {
        uint32_t b1 = j ? u1b : u1a;
        uint32_t b2 = j ? u2b : u2a;
        int i1 = (int)(bits_to_unit_float(b1) * tf);
        int i2 = (int)(bits_to_unit_float(b2) * tf);
        int r = mask_idx[i1];
        int c = mask_idx[i2];
        size_t o1 = (size_t)r * n + c;
        size_t o2 = (size_t)c * n + r;
        dec[o1] = comp[o1];
        dec[o2] = comp[o2];
    }
}

// ---------------- launch ----------------
extern "C" void kernel_launch(void* const* d_in, const int* in_sizes, int n_in,
                              void* d_out, int out_size, void* d_ws, size_t ws_size,
                              hipStream_t stream) {
    const int*   rows  = (const int*)d_in[0];
    const int*   cols  = (const int*)d_in[1];
    // d_in[2] = adj_values — unused by the forward
    const int*   seeds = (const int*)d_in[3];
    const float* comp  = (const float*)d_in[4];

    const int nnz     = in_sizes[0];
    const int n_seeds = in_sizes[3];
    const int n       = (int)(sqrt((double)in_sizes[4]) + 0.5);   // 8192

    float* enc = (float*)d_out;
    float* dec = enc + (size_t)n * n;

    // ---- small workspace region (~385 KB, the only workspace required) ----
    char* ws = (char*)d_ws;
    float* deg            = (float*)(ws);
    float* nrm            = (float*)(ws + 4 * (size_t)n);
    int*   mask_idx       = (int*)  (ws + 8 * (size_t)n);
    int*   tem_num        = (int*)  (ws + 12 * (size_t)n);
    unsigned char* seedm  = (unsigned char*)(ws + 12 * (size_t)n + 256);
    unsigned char* nxt    = seedm + n;
    unsigned char* mask   = nxt + n;
    unsigned char* keep   = mask + n;   // nnz bytes, fully written each call

    const int B = 256;
    int samp_num = (int)((double)n * 0.9);   // int(N*0.9) = 7372 (even)
    int shalf = samp_num / 2;
    int ehalf = nnz / 2;

    // zero: deg..tem_num + seedm/nxt/mask (NOT keep — fully written by k_edge1)
    size_t zbytes = 12 * (size_t)n + 256 + 3 * (size_t)n;
    hipMemsetAsync(d_ws, 0, zbytes, stream);

    k_seed <<<(n_seeds + B - 1) / B, B, 0, stream>>>(seeds, n_seeds, seedm);
    k_edge1<<<(nnz + B - 1) / B, B, 0, stream>>>(rows, cols, nnz, seedm, keep, nxt);
    k_edge2<<<(nnz + B - 1) / B, B, 0, stream>>>(rows, cols, nnz, nxt, keep);
    k_union<<<(n + B - 1) / B, B, 0, stream>>>(n, seedm, nxt, mask);
    k_samp <<<(shalf + B - 1) / B, B, 0, stream>>>(shalf, n - 1, mask);
    k_scan <<<1, 1024, 0, stream>>>(n, mask, mask_idx, tem_num);
    k_deg  <<<(nnz + B - 1) / B, B, 0, stream>>>(rows, cols, nnz, keep, comp, deg, n);
    k_norm <<<(n + B - 1) / B, B, 0, stream>>>(n, deg, nrm);

    if (n == 8192) {
        u32* decw = (u32*)dec;
        k_zslice<<<256, 256, 0, stream>>>(decw);
        int total = nnz + n + ehalf;
        k_cov   <<<(total + B - 1) / B, B, 0, stream>>>(rows, cols, nnz, n, ehalf,
                                                        keep, mask_idx, tem_num, decw);
        k_dense2<<<256, 512, 0, stream>>>(n, comp, nrm, enc, dec);
    } else {
        // legacy scattered path for unexpected shapes
        hipMemsetAsync(d_out, 0, 2 * (size_t)n * (size_t)n * sizeof(float), stream);
        k_enc  <<<(nnz + B - 1) / B, B, 0, stream>>>(rows, cols, nnz, keep, comp, nrm, enc, n);
        k_dec_base<<<(nnz + n + B - 1) / B, B, 0, stream>>>(rows, cols, nnz, n, keep, comp, dec);
        k_dec_tem<<<(ehalf + B - 1) / B, B, 0, stream>>>(ehalf, n, mask_idx, tem_num, comp, dec);
    }
}

// Round 5
// 735.840 us; speedup vs baseline: 1.5373x; 1.0215x over previous
//
#include <hip/hip_runtime.h>
#include <stdint.h>
#include <math.h>

typedef float f4 __attribute__((ext_vector_type(4)));
typedef unsigned int u32;
typedef uint4 u32x4;

// ---------------- Threefry-2x32 (exact JAX replication) ----------------
static __device__ __forceinline__ uint32_t rotl32(uint32_t x, int r) {
    return (x << r) | (x >> (32 - r));
}

static __device__ __forceinline__ void tf2x32(uint32_t k0, uint32_t k1,
                                              uint32_t& x0, uint32_t& x1) {
    uint32_t ks2 = k0 ^ k1 ^ 0x1BD11BDAu;
    x0 += k0; x1 += k1;
#define TFR(r) { x0 += x1; x1 = rotl32(x1, r); x1 ^= x0; }
    TFR(13) TFR(15) TFR(26) TFR(6)
    x0 += k1;  x1 += ks2 + 1u;
    TFR(17) TFR(29) TFR(16) TFR(24)
    x0 += ks2; x1 += k0 + 2u;
    TFR(13) TFR(15) TFR(26) TFR(6)
    x0 += k0;  x1 += k1 + 3u;
    TFR(17) TFR(29) TFR(16) TFR(24)
    x0 += k1;  x1 += ks2 + 4u;
    TFR(13) TFR(15) TFR(26) TFR(6)
    x0 += ks2; x1 += k0 + 5u;
#undef TFR
}

// jax.random.split(key(42), 3): k1=(a0,a1) k2=(a2,b0) k3=(b1,b2)
struct SubKeys { uint32_t k1a, k1b, k2a, k2b, k3a, k3b; };

static __device__ __forceinline__ SubKeys derive_keys() {
    uint32_t a0 = 0, b0 = 3; tf2x32(0u, 42u, a0, b0);
    uint32_t a1 = 1, b1 = 4; tf2x32(0u, 42u, a1, b1);
    uint32_t a2 = 2, b2 = 5; tf2x32(0u, 42u, a2, b2);
    SubKeys s; s.k1a = a0; s.k1b = a1; s.k2a = a2; s.k2b = b0; s.k3a = b1; s.k3b = b2;
    return s;
}

static __device__ __forceinline__ float bits_to_unit_float(uint32_t b) {
    return __uint_as_float((b >> 9) | 0x3f800000u) - 1.0f;
}

// ---------------- pipeline kernels ----------------
__global__ void k_seed(const int* __restrict__ seeds, int n_seeds,
                       unsigned char* __restrict__ seedm) {
    int i = blockIdx.x * blockDim.x + threadIdx.x;
    if (i < n_seeds) seedm[seeds[i]] = 1;
}

__global__ void k_edge1(const int* __restrict__ rows, const int* __restrict__ cols, int nnz,
                        const unsigned char* __restrict__ seedm,
                        unsigned char* __restrict__ keep, unsigned char* __restrict__ nxt) {
    int e = blockIdx.x * blockDim.x + threadIdx.x;
    if (e >= nnz) return;
    int r = rows[e], c = cols[e];
    bool inc = (seedm[r] | seedm[c]) != 0;
    keep[e] = inc ? 0 : 1;
    if (inc) { nxt[r] = 1; nxt[c] = 1; }   // same-value byte stores, race-safe
}

// fused: finalize keep (depth-2 removal) + accumulate deg for kept edges.
// per-edge result depends only on its own keep + nxt -> identical to the
// old k_edge2; k_deg sequence.
__global__ void k_edge2deg(const int* __restrict__ rows, const int* __restrict__ cols,
                           int nnz, int n,
                           const unsigned char* __restrict__ nxt,
                           unsigned char* __restrict__ keep,
                           const float* __restrict__ comp, float* __restrict__ deg) {
    int e = blockIdx.x * blockDim.x + threadIdx.x;
    if (e >= nnz) return;
    int r = rows[e], c = cols[e];
    bool kv = keep[e] && ((nxt[r] | nxt[c]) == 0);
    keep[e] = kv ? 1 : 0;
    if (kv) atomicAdd(&deg[r], comp[(size_t)r * n + c]);
}

// samped = randint(k1,(samp_num,),0,N) with N=2^13 -> bits & (N-1); bitmap out.
__global__ void k_samp(int half, int modmask, u32* __restrict__ sampw) {
    int t = blockIdx.x * blockDim.x + threadIdx.x;
    if (t >= half) return;
    SubKeys sk = derive_keys();
    uint32_t x0 = (uint32_t)t, x1 = (uint32_t)(t + half);
    tf2x32(sk.k1a, sk.k1b, x0, x1);
    x0 &= (uint32_t)modmask; x1 &= (uint32_t)modmask;
    atomicOr(&sampw[x0 >> 5], 1u << (x0 & 31));
    atomicOr(&sampw[x1 >> 5], 1u << (x1 & 31));
}

// single-block scan over mask = seedm|nxt|samp -> ascending mask_idx + tem_num
__global__ void __launch_bounds__(1024)
k_scan(int n, const unsigned char* __restrict__ seedm,
       const unsigned char* __restrict__ nxt, const u32* __restrict__ sampw,
       int* __restrict__ mask_idx, int* __restrict__ tem_num) {
    __shared__ int ssum[1024];
    int t = threadIdx.x;
    int per = n / 1024;           // 8 for n=8192
    int base = t * per;
    int loc[8];
    int s = 0;
    for (int j = 0; j < per; ++j) {
        int i = base + j;
        int v = ((seedm[i] | nxt[i]) != 0) | ((sampw[i >> 5] >> (i & 31)) & 1u);
        loc[j] = v; s += v;
    }
    ssum[t] = s;
    __syncthreads();
    for (int off = 1; off < 1024; off <<= 1) {
        int v = (t >= off) ? ssum[t - off] : 0;
        __syncthreads();
        ssum[t] += v;
        __syncthreads();
    }
    int excl = ssum[t] - s;
    for (int j = 0; j < per; ++j)
        if (loc[j]) mask_idx[excl++] = base + j;
    if (t == 1023) *tem_num = ssum[1023];
}

__global__ void k_norm(int n, const float* __restrict__ deg, float* __restrict__ nrm) {
    int i = blockIdx.x * blockDim.x + threadIdx.x;
    if (i < n) nrm[i] = 1.0f / sqrtf(deg[i] + 1e-12f);
}

// ---------------- fast path (n==8192): scratch-in-window coverage bitmaps ----------------
// Window b = dec rows [8b, 8b+8)  (8 rows * 8192 floats = 256 KB).
// Its 16KB bitmap slice lives in its OWN first half-row:
//   slice(b) = (u32*)dec + b*65536 ; words [0,2048)=dec bits, [2048,4096)=enc bits
// word index within a map: ((row&7)<<8) + (col>>5). One block per window ->
// no cross-block ordering needed (block loads slice to LDS, then overwrites).
#define WIN8  65536        // u32 stride between windows (8 rows * 8192)
#define SLW8  4096         // u32 words per slice (2 * 8 * 256)

__global__ void __launch_bounds__(256)
k_zslice(u32* __restrict__ decw) {
    u32x4* s4 = (u32x4*)(decw + (size_t)blockIdx.x * WIN8);
    u32x4 z = {0u, 0u, 0u, 0u};
    for (int i = threadIdx.x; i < SLW8 / 4; i += 256) s4[i] = z;
}

// one pass: kept edges (enc+dec), diagonal (dec), tem RNG pairs (dec, symmetric)
__global__ void __launch_bounds__(256)
k_cov(const int* __restrict__ rows, const int* __restrict__ cols,
      int nnz, int n, int ehalf,
      const unsigned char* __restrict__ keep,
      const int* __restrict__ mask_idx, const int* __restrict__ tem_num,
      u32* __restrict__ decw) {
    int e = blockIdx.x * blockDim.x + threadIdx.x;
    if (e < nnz) {
        if (keep[e]) {
            int r = rows[e], c = cols[e];
            u32* base = decw + (size_t)(r >> 3) * WIN8;
            int w = ((r & 7) << 8) + (c >> 5);
            u32 b = 1u << (c & 31);
            atomicOr(&base[w], b);            // dec bit
            atomicOr(&base[2048 + w], b);     // enc bit
        }
    } else if (e < nnz + n) {
        int i = e - nnz;
        atomicOr(&decw[(size_t)(i >> 3) * WIN8 + ((i & 7) << 8) + (i >> 5)],
                 1u << (i & 31));             // self loop (dec)
    } else if (e < nnz + n + ehalf) {
        int q = e - nnz - n;
        SubKeys sk = derive_keys();
        float tf = (float)(*tem_num);
        uint32_t u1a = (uint32_t)q, u1b = (uint32_t)(q + ehalf);
        tf2x32(sk.k2a, sk.k2b, u1a, u1b);
        uint32_t u2a = (uint32_t)q, u2b = (uint32_t)(q + ehalf);
        tf2x32(sk.k3a, sk.k3b, u2a, u2b);
#pragma unroll
        for (int j = 0; j < 2; ++j) {
            uint32_t b1 = j ? u1b : u1a;
            uint32_t b2 = j ? u2b : u2a;
            int i1 = (int)(bits_to_unit_float(b1) * tf);   // floor==trunc, f32 RN == jnp
            int i2 = (int)(bits_to_unit_float(b2) * tf);
            int r = mask_idx[i1];
            int c = mask_idx[i2];
            atomicOr(&decw[(size_t)(r >> 3) * WIN8 + ((r & 7) << 8) + (c >> 5)],
                     1u << (c & 31));
            atomicOr(&decw[(size_t)(c >> 3) * WIN8 + ((c & 7) << 8) + (r >> 5)],
                     1u << (r & 31));
        }
    }
}

// pure streamer: 1024 blocks x 256 threads, 16KB LDS -> 4 blocks/CU (50% occ).
// Load own slice -> LDS, then write 8 enc+dec rows fused, nontemporal f4.
__global__ void __launch_bounds__(256)
k_dense3(int n, const float* __restrict__ comp, const float* __restrict__ nrm,
         float* __restrict__ enc, float* __restrict__ dec) {
    __shared__ u32 sbm[SLW8];                 // [0,2048)=dec, [2048,4096)=enc
    const int t = threadIdx.x;
    const int b = blockIdx.x;
    {
        const u32x4* s4 = (const u32x4*)((const u32*)dec + (size_t)b * WIN8);
        u32x4* l4 = (u32x4*)sbm;
#pragma unroll
        for (int i = 0; i < SLW8 / 4 / 256; ++i)   // 4 iters
            l4[i * 256 + t] = s4[i * 256 + t];
    }
    __syncthreads();
    const int base = b * 8;
    const f4* nrmv = (const f4*)nrm;
#pragma unroll
    for (int i = 0; i < 8; ++i) {
        int r = base + i;
        float nr = nrm[r];
        size_t rowo = (size_t)r * n;
        const f4* compv = (const f4*)(comp + rowo);
        f4* encv = (f4*)(enc + rowo);
        f4* decv = (f4*)(dec + rowo);
        int wrow = i << 8;
#pragma unroll
        for (int k = 0; k < 8; ++k) {         // 2048 f4 / 256 threads
            int f = k * 256 + t;
            int sh = (f & 7) * 4;
            u32 dw = (sbm[wrow + (f >> 3)] >> sh) & 0xFu;
            u32 ew = (sbm[2048 + wrow + (f >> 3)] >> sh) & 0xFu;
            f4 ev = {0.f, 0.f, 0.f, 0.f};
            f4 dv = {0.f, 0.f, 0.f, 0.f};
            if (ew | dw) {
                f4 cv = compv[f];
                if (dw & 1u) dv.x = cv.x;
                if (dw & 2u) dv.y = cv.y;
                if (dw & 4u) dv.z = cv.z;
                if (dw & 8u) dv.w = cv.w;
                if (ew) {
                    f4 nv = nrmv[f];
                    if (ew & 1u) ev.x = cv.x * nr * nv.x;
                    if (ew & 2u) ev.y = cv.y * nr * nv.y;
                    if (ew & 4u) ev.z = cv.z * nr * nv.z;
                    if (ew & 8u) ev.w = cv.w * nr * nv.w;
                }
            }
            __builtin_nontemporal_store(ev, &encv[f]);
            __builtin_nontemporal_store(dv, &decv[f]);
        }
    }
}

// ---------------- fallback path (verified scattered kernels, n != 8192) ----------------
__global__ void k_enc(const int* __restrict__ rows, const int* __restrict__ cols, int nnz,
                      const unsigned char* __restrict__ keep,
                      const float* __restrict__ comp, const float* __restrict__ nrm,
                      float* __restrict__ enc, int n) {
    int e = blockIdx.x * blockDim.x + threadIdx.x;
    if (e >= nnz) return;
    if (keep[e]) {
        int r = rows[e], c = cols[e];
        size_t o = (size_t)r * n + c;
        enc[o] = comp[o] * nrm[r] * nrm[c];
    }
}

__global__ void k_dec_base(const int* __restrict__ rows, const int* __restrict__ cols,
                           int nnz, int n, const unsigned char* __restrict__ keep,
                           const float* __restrict__ comp, float* __restrict__ dec) {
    int e = blockIdx.x * blockDim.x + threadIdx.x;
    if (e < nnz) {
        if (keep[e]) {
            size_t o = (size_t)rows[e] * n + cols[e];
            dec[o] = comp[o];
        }
    } else if (e < nnz + n) {
        int i = e - nnz;
        size_t o = (size_t)i * n + i;
        dec[o] = comp[o];
    }
}

__global__ void k_dec_tem(int half, int n, const int* __restrict__ mask_idx,
                          const int* __restrict__ tem_num,
                          const float* __restrict__ comp, float* __restrict__ dec) {
    int e = blockIdx.x * blockDim.x + threadIdx.x;
    if (e >= half) return;
    SubKeys sk = derive_keys();
    float tf = (float)(*tem_num);
    uint32_t u1a = (uint32_t)e, u1b = (uint32_t)(e + half);
    tf2x32(sk.k2a, sk.k2b, u1a, u1b);
    uint32_t u2a = (uint32_t)e, u2b = (uint32_t)(e + half);
    tf2x32(sk.k3a, sk.k3b, u2a, u2b);
#pragma unroll
    for (int j = 0; j < 2; ++j) {
        uint32_t b1 = j ? u1b : u1a;
        uint32_t b2 = j ? u2b : u2a;
        int i1 = (int)(bits_to_unit_float(b1) * tf);
        int i2 = (int)(bits_to_unit_float(b2) * tf);
        int r = mask_idx[i1];
        int c = mask_idx[i2];
        size_t o1 = (size_t)r * n + c;
        size_t o2 = (size_t)c * n + r;
        dec[o1] = comp[o1];
        dec[o2] = comp[o2];
    }
}

// ---------------- launch ----------------
extern "C" void kernel_launch(void* const* d_in, const int* in_sizes, int n_in,
                              void* d_out, int out_size, void* d_ws, size_t ws_size,
                              hipStream_t stream) {
    const int*   rows  = (const int*)d_in[0];
    const int*   cols  = (const int*)d_in[1];
    // d_in[2] = adj_values — unused by the forward
    const int*   seeds = (const int*)d_in[3];
    const float* comp  = (const float*)d_in[4];

    const int nnz     = in_sizes[0];
    const int n_seeds = in_sizes[3];
    const int n       = (int)(sqrt((double)in_sizes[4]) + 0.5);   // 8192

    float* enc = (float*)d_out;
    float* dec = enc + (size_t)n * n;

    // ---- small workspace region (~0.4 MB, the only workspace required) ----
    char* ws = (char*)d_ws;
    float* deg            = (float*)(ws);                          // 4n
    float* nrm            = (float*)(ws + 4 * (size_t)n);          // 4n
    int*   mask_idx       = (int*)  (ws + 8 * (size_t)n);          // 4n
    int*   tem_num        = (int*)  (ws + 12 * (size_t)n);         // 256 B pad
    u32*   sampw          = (u32*)  (ws + 12 * (size_t)n + 256);   // n/8
    unsigned char* seedm  = (unsigned char*)(ws + 12 * (size_t)n + 256 + (size_t)n / 8);
    unsigned char* nxt    = seedm + n;
    unsigned char* keep   = nxt + n;   // nnz bytes, fully written by k_edge1

    const int B = 256;
    int samp_num = (int)((double)n * 0.9);   // int(N*0.9) = 7372 (even)
    int shalf = samp_num / 2;
    int ehalf = nnz / 2;

    // zero: deg..tem_num + sampw + seedm + nxt (NOT keep)
    size_t zbytes = 12 * (size_t)n + 256 + (size_t)n / 8 + 2 * (size_t)n;
    hipMemsetAsync(d_ws, 0, zbytes, stream);

    k_seed    <<<(n_seeds + B - 1) / B, B, 0, stream>>>(seeds, n_seeds, seedm);
    k_edge1   <<<(nnz + B - 1) / B, B, 0, stream>>>(rows, cols, nnz, seedm, keep, nxt);
    k_samp    <<<(shalf + B - 1) / B, B, 0, stream>>>(shalf, n - 1, sampw);
    k_edge2deg<<<(nnz + B - 1) / B, B, 0, stream>>>(rows, cols, nnz, n, nxt, keep, comp, deg);
    k_scan    <<<1, 1024, 0, stream>>>(n, seedm, nxt, sampw, mask_idx, tem_num);
    k_norm    <<<(n + B - 1) / B, B, 0, stream>>>(n, deg, nrm);

    if (n == 8192) {
        u32* decw = (u32*)dec;
        k_zslice<<<n / 8, B, 0, stream>>>(decw);
        int total = nnz + n + ehalf;
        k_cov   <<<(total + B - 1) / B, B, 0, stream>>>(rows, cols, nnz, n, ehalf,
                                                        keep, mask_idx, tem_num, decw);
        k_dense3<<<n / 8, B, 0, stream>>>(n, comp, nrm, enc, dec);
    } else {
        // legacy scattered path for unexpected shapes
        hipMemsetAsync(d_out, 0, 2 * (size_t)n * (size_t)n * sizeof(float), stream);
        k_enc  <<<(nnz + B - 1) / B, B, 0, stream>>>(rows, cols, nnz, keep, comp, nrm, enc, n);
        k_dec_base<<<(nnz + n + B - 1) / B, B, 0, stream>>>(rows, cols, nnz, n, keep, comp, dec);
        k_dec_tem<<<(ehalf + B - 1) / B, B, 0, stream>>>(ehalf, n, mask_idx, tem_num, comp, dec);
    }
}